// Round 1
// baseline (22710.371 us; speedup 1.0000x reference)
//
#include <hip/hip_runtime.h>
#include <cstddef>
#include <cstdint>

#define HID     1024
#define BATCH   64
#define TSEQ    512
#define NB      (BATCH*HID)     // 65536 floats per [B,H] slab
#define NBLK    256
#define NITER   515
#define RSTRIDE 20              // LDS reduction row stride (16 + pad 4)

// ---------------------------------------------------------------------------
// ws layout (floats):
//  [0*NB, 2*NB)  h0 ping-pong   (slot t&1 holds h0[t])
//  [2*NB, 4*NB)  h1 ping-pong   (slot t&1 holds h1[t])
//  [4*NB, 6*NB)  ig1 ping-pong  (slot t&1 holds igate1[t] + bx1 + bh1)
//  [6*NB]        barrier counter (unsigned, zeroed by hipMemsetAsync)
//
// Coherence model (replaces the old agent release/acquire fences):
//  - every cross-block slab access uses agent-scope (sc1) loads/stores:
//    stores write through to the MALL (device coherence point), loads bypass
//    L1/L2 and read the MALL. No buffer_wbl2/buffer_inv per iteration ->
//    the W working set (64 KB/block, scalar-load path) stays L2-resident
//    across all 515 iterations.
//  - gbar: explicit s_waitcnt vmcnt(0) per wave (stores drained to MALL)
//    -> s_barrier -> relaxed agent fetch_add / relaxed agent poll.
// ---------------------------------------------------------------------------

typedef __attribute__((ext_vector_type(4))) float f32x4;
typedef __attribute__((ext_vector_type(2))) float f32x2;

// manual vmcnt discipline: sched_barrier(0) after each wait keeps hipcc from
// hoisting register-only consumers above the wait (guide rule #18).
#define WAITV(N) do { asm volatile("s_waitcnt vmcnt(" #N ")" ::: "memory"); \
                      __builtin_amdgcn_sched_barrier(0); } while (0)

template<bool COH>
__device__ __forceinline__ f32x4 gload4(const float* p) {
  f32x4 v;
  if constexpr (COH)
    asm volatile("global_load_dwordx4 %0, %1, off sc1" : "=v"(v) : "v"(p) : "memory");
  else
    asm volatile("global_load_dwordx4 %0, %1, off"     : "=v"(v) : "v"(p) : "memory");
  return v;
}

__device__ __forceinline__ f32x2 gload2_coh(const float* p) {
  f32x2 v;
  asm volatile("global_load_dwordx2 %0, %1, off sc1" : "=v"(v) : "v"(p) : "memory");
  return v;
}

__device__ __forceinline__ void gstore2_coh(float* p, f32x2 v) {
  asm volatile("global_store_dwordx2 %0, %1, off sc1" :: "v"(p), "v"(v) : "memory");
}

__device__ __forceinline__ void gbar(unsigned* bar, unsigned target) {
  // Drain this wave's (write-through) stores to the coherence point, then
  // block-barrier so ALL waves' stores are drained before thread 0 arrives.
  asm volatile("s_waitcnt vmcnt(0)" ::: "memory");
  __syncthreads();
  if (threadIdx.x == 0) {
    __hip_atomic_fetch_add(bar, 1u, __ATOMIC_RELAXED, __HIP_MEMORY_SCOPE_AGENT);
    while (__hip_atomic_load(bar, __ATOMIC_RELAXED, __HIP_MEMORY_SCOPE_AGENT) < target) {
      __builtin_amdgcn_s_sleep(1);
    }
  }
  __syncthreads();
}

// 16-col x 32-k FMA section. W addresses are wave-uniform (kq via
// readfirstlane) -> scalar s_loads on the SMEM pipe, L2-resident.
__device__ __forceinline__ void fma16(float acc[16], const f32x4 h[8], const float* Wc) {
#pragma unroll 4
  for (int c = 0; c < 16; ++c) {
    const float* w = Wc + (size_t)c * HID;
    float s = acc[c];
#pragma unroll
    for (int r = 0; r < 8; ++r) {
      float4 wv = *(const float4*)(w + r * 4);
      s += h[r].x * wv.x;
      s += h[r].y * wv.y;
      s += h[r].z * wv.z;
      s += h[r].w * wv.w;
    }
    acc[c] = s;
  }
}

// Dot engine: 16 cols over a private K-slice of 128, explicit A/B register
// double-buffer with counted vmcnt (8 = the just-issued prefetch batch).
// FIFO vmcnt semantics make the waits safe even with extra older loads
// (e-prefetch) in flight.
template<bool COH>
__device__ __forceinline__ void dot_engine(const float* hb, const float* Wb, float acc[16]) {
  f32x4 A[8], B[8];
#pragma unroll
  for (int r = 0; r < 8; ++r) A[r] = gload4<COH>(hb + r * 4);
#pragma unroll
  for (int r = 0; r < 8; ++r) B[r] = gload4<COH>(hb + 32 + r * 4);
  WAITV(8);                 // A ready (newest 8 = B still in flight)
  fma16(acc, A, Wb);
#pragma unroll
  for (int r = 0; r < 8; ++r) A[r] = gload4<COH>(hb + 64 + r * 4);
  WAITV(8);                 // B ready
  fma16(acc, B, Wb + 32);
#pragma unroll
  for (int r = 0; r < 8; ++r) B[r] = gload4<COH>(hb + 96 + r * 4);
  WAITV(8);                 // A(ch2) ready
  fma16(acc, A, Wb + 64);
  WAITV(0);                 // B(ch3) + epilogue prefetch ready
  fma16(acc, B, Wb + 96);
}

// ---------------------------------------------------------------------------
// Persistent cooperative pipelined recurrence, 256 blocks x 512 threads.
// Roles (blk>>6), iteration i:
//   3: ig0[t=i]   = x[t] @ Wx0^T + bx0 + bh0      -> io[t]   (coh store)
//   0: h0[t=i-1]  = tanh(ig0[t] + h0[t-1] @ Wh0^T) -> slot t&1
//   1: ig1[t=i-2] = h0[t] @ Wx1^T + bx1 + bh1      -> slot t&1
//   2: h1[t=i-3]  = tanh(ig1[t] + h1[t-1] @ Wh1^T); io[t] = 10*h1 (plain)
// ---------------------------------------------------------------------------
__global__ __launch_bounds__(512, 2) void rnn_step(
    const float* __restrict__ x,
    float* io,                          // d_out: ig0 scratch AND output sink
    const float* __restrict__ h0_init,  // [2][B][H]
    const float* __restrict__ Wx,       // [2][H][H]
    const float* __restrict__ Wh,       // [2][H][H]
    const float* __restrict__ bx,       // [2][H]
    const float* __restrict__ bh,       // [2][H]
    float* __restrict__ ws)
{
  __shared__ __align__(16) float red[8 * 64 * RSTRIDE];   // 40 KB
  const int tid  = threadIdx.x;
  const int blk  = blockIdx.x;
  const int role = blk >> 6;                 // 0..3
  const int c0   = (blk & 63) << 4;          // 16 cols per block
  const int b    = tid & 63;
  const int kq   = __builtin_amdgcn_readfirstlane(tid >> 6); // wave id 0..7

  float* h0s[2]  = { ws,                ws + (size_t)NB   };
  float* h1s[2]  = { ws + 2*(size_t)NB, ws + 3*(size_t)NB };
  float* ig1s[2] = { ws + 4*(size_t)NB, ws + 5*(size_t)NB };
  unsigned* bar  = (unsigned*)(ws + 6*(size_t)NB);

  const float* W = (role == 3) ? Wx
                 : (role == 0) ? Wh
                 : (role == 1) ? (Wx + (size_t)HID * HID)
                 :               (Wh + (size_t)HID * HID);
  const float* Wb = W + (size_t)c0 * HID + kq * 128;

  // Epilogue output assignment: 2 outputs per thread, o = 2*tid, 2*tid+1.
  const int o0 = tid * 2;
  const int b1 = o0 >> 4;                    // batch row of outputs
  const int c1 = o0 & 15;                    // local col (even)
  const size_t rb = (size_t)b1 * HID + c0 + c1;

  float bsum0 = 0.f, bsum1 = 0.f;
  if (role == 1) {
    bsum0 = bx[HID + c0 + c1]     + bh[HID + c0 + c1];
    bsum1 = bx[HID + c0 + c1 + 1] + bh[HID + c0 + c1 + 1];
  } else if (role == 3) {
    bsum0 = bx[c0 + c1]     + bh[c0 + c1];
    bsum1 = bx[c0 + c1 + 1] + bh[c0 + c1 + 1];
  }

  for (int i = 0; i < NITER; ++i) {
    bool active;
    const float* src;
    if (role == 3)      { active = (i <= 511);           src = x + (size_t)i * NB; }
    else if (role == 0) { active = (i >= 1 && i <= 512); src = (i == 1) ? h0_init        : h0s[i & 1]; }
    else if (role == 1) { active = (i >= 2 && i <= 513); src = h0s[i & 1]; }
    else                { active = (i >= 3 && i <= 514); src = (i == 3) ? (h0_init + NB) : h1s[i & 1]; }

    if (active) {
      // Prefetch epilogue operands early (produced last iteration).
      f32x2 e = { 0.f, 0.f };
      if (role == 0)      e = gload2_coh(io + (size_t)(i - 1) * NB + rb);
      else if (role == 2) e = gload2_coh(ig1s[(i - 1) & 1] + rb);

      const float* hb = src + (size_t)b * HID + kq * 128;  // private K-slice

      float acc[16];
#pragma unroll
      for (int c = 0; c < 16; ++c) acc[c] = 0.f;

      if (role == 3) dot_engine<false>(hb, Wb, acc);   // x: plain, L2-cacheable
      else           dot_engine<true >(hb, Wb, acc);   // slabs: agent-coherent

      // kq-reduction through LDS (row stride 20 words).
      float* rrow = &red[(kq * 64 + b) * RSTRIDE];
      *(float4*)(rrow + 0)  = make_float4(acc[0],  acc[1],  acc[2],  acc[3]);
      *(float4*)(rrow + 4)  = make_float4(acc[4],  acc[5],  acc[6],  acc[7]);
      *(float4*)(rrow + 8)  = make_float4(acc[8],  acc[9],  acc[10], acc[11]);
      *(float4*)(rrow + 12) = make_float4(acc[12], acc[13], acc[14], acc[15]);
      __syncthreads();

      float s0 = 0.f, s1 = 0.f;
#pragma unroll
      for (int q = 0; q < 8; ++q) {
        s0 += red[(q * 64 + b1) * RSTRIDE + c1];
        s1 += red[(q * 64 + b1) * RSTRIDE + c1 + 1];
      }

      if (role == 3) {
        f32x2 o = { s0 + bsum0, s1 + bsum1 };
        gstore2_coh(io + (size_t)i * NB + rb, o);
      } else if (role == 0) {
        f32x2 o = { tanhf(s0 + e.x), tanhf(s1 + e.y) };
        gstore2_coh(h0s[(i - 1) & 1] + rb, o);
      } else if (role == 1) {
        f32x2 o = { s0 + bsum0, s1 + bsum1 };
        gstore2_coh(ig1s[i & 1] + rb, o);
      } else {
        const int t = i - 3;
        float t0 = tanhf(s0 + e.x);
        float t1 = tanhf(s1 + e.y);
        f32x2 o = { t0, t1 };
        gstore2_coh(h1s[(i - 1) & 1] + rb, o);
        // Final output: plain store, flushed at kernel end (nobody re-reads
        // io[t] after this point during the kernel).
        *(float2*)&io[(size_t)t * NB + rb] = make_float2(10.f * t0, 10.f * t1);
      }
      // red reuse next iter is fenced by gbar's __syncthreads.
    }
    gbar(bar, (unsigned)(NBLK * (i + 1)));
  }
}

// ---------------------------------------------------------------------------
// Finalize: h_n = [h0[511], h1[511]] (both in ping-pong slot 1; written by
// sc1 write-through stores -> visible after dispatch boundary).
// ---------------------------------------------------------------------------
__global__ __launch_bounds__(256) void finalize_hn(
    const float* __restrict__ ws, float* __restrict__ out)
{
  const int g = blockIdx.x * 256 + threadIdx.x;     // 0..131071
  const float* h0f = ws + NB;                       // h0 slot 1
  const float* h1f = ws + 3 * (size_t)NB;           // h1 slot 1
  const float v = (g < NB) ? h0f[g] : h1f[g - NB];
  out[(size_t)TSEQ * NB + g] = v;
}

// ---------------------------------------------------------------------------
extern "C" void kernel_launch(void* const* d_in, const int* in_sizes, int n_in,
                              void* d_out, int out_size, void* d_ws, size_t ws_size,
                              hipStream_t stream) {
  const float* x  = (const float*)d_in[0];
  const float* h0 = (const float*)d_in[1];
  const float* Wx = (const float*)d_in[2];
  const float* bx = (const float*)d_in[3];
  const float* Wh = (const float*)d_in[4];
  const float* bh = (const float*)d_in[5];
  float* out = (float*)d_out;
  float* ws  = (float*)d_ws;

  // Zero the barrier counter (stream-ordered, graph-capture safe).
  hipMemsetAsync(ws + 6 * (size_t)NB, 0, sizeof(unsigned), stream);

  float* io = out;
  void* args[] = { &x, &io, &h0, &Wx, &Wh, &bx, &bh, &ws };
  hipLaunchCooperativeKernel((const void*)rnn_step, dim3(NBLK), dim3(512),
                             args, 0, stream);

  finalize_hn<<<dim3(512), dim3(256), 0, stream>>>(ws, out);
}

// Round 4
// 19346.870 us; speedup vs baseline: 1.1739x; 1.1739x over previous
//
#include <hip/hip_runtime.h>
#include <cstddef>
#include <cstdint>

#define HID     1024
#define BATCH   64
#define TSEQ    512
#define NB      (BATCH*HID)     // 65536 floats per [B,H] slab
#define NBLK    256
#define NITER   515
#define RSTRIDE 20              // LDS reduction row stride (16 + pad 4)

// ---------------------------------------------------------------------------
// ws layout (floats), P = slot rotation depth (16/8/4/2 chosen from ws_size):
//  [0,            P*NB)    h0 slots   (slot t&(P-1) holds h0[t])
//  [P*NB,       2*P*NB)    h1 slots
//  [2*P*NB,     3*P*NB)    ig1 slots  (igate1[t] + bx1 + bh1)
//  [3*P*NB]                barrier counter (unsigned, zeroed by memset)
//
// Coherence model:
//  - cross-block slab STORES are sc1 write-through: data reaches the MALL
//    (device coherence point) before the barrier count increments;
//    invalidation can never lose data.
//  - slab LOADS are PLAIN (L1/L2 cached): the same-role blocks on one XCD
//    share a single 256 KB L2 fetch per slab per iteration (8x dedup vs sc1).
//  - staleness: slot S of a slab is read exactly once per P iterations,
//    rewritten once per P; the agent-acquire fence (L1+L2 invalidate) fires
//    at iters == 0 mod P, so exactly one fence lands between any cache-fill
//    of a slot line and the next read of that slot, with no intervening
//    re-read. If the fence lands on the reading iteration itself it precedes
//    the loads (loop-top fence) -> fresh fetch. Verified for all four
//    producer->consumer edges incl. boundary cases.
//  - io[t] (ig0 / final out) addresses are write-once within a run -> plain
//    reads are always cold-or-fresh. Across graph replays the dispatch
//    acquire invalidates caches.
//  - W is read-only -> L2-resident; refetched once per fence (amortized
//    over P iterations).
// ---------------------------------------------------------------------------

typedef __attribute__((ext_vector_type(4))) float f32x4;
typedef __attribute__((ext_vector_type(2))) float f32x2;

// manual vmcnt discipline: sched_barrier(0) after each wait keeps hipcc from
// hoisting register-only consumers above the wait (guide rule #18).
#define WAITV(N) do { asm volatile("s_waitcnt vmcnt(" #N ")" ::: "memory"); \
                      __builtin_amdgcn_sched_barrier(0); } while (0)

__device__ __forceinline__ f32x4 gload4(const float* p) {
  f32x4 v;
  asm volatile("global_load_dwordx4 %0, %1, off" : "=v"(v) : "v"(p) : "memory");
  return v;
}

__device__ __forceinline__ f32x2 gload2(const float* p) {
  f32x2 v;
  asm volatile("global_load_dwordx2 %0, %1, off" : "=v"(v) : "v"(p) : "memory");
  return v;
}

__device__ __forceinline__ void gstore2_coh(float* p, f32x2 v) {
  asm volatile("global_store_dwordx2 %0, %1, off sc1" :: "v"(p), "v"(v) : "memory");
}

__device__ __forceinline__ void gbar(unsigned* bar, unsigned target) {
  // Drain this wave's write-through stores to the coherence point, then
  // block-barrier so ALL waves' stores are drained before thread 0 arrives.
  asm volatile("s_waitcnt vmcnt(0)" ::: "memory");
  __syncthreads();
  if (threadIdx.x == 0) {
    __hip_atomic_fetch_add(bar, 1u, __ATOMIC_RELAXED, __HIP_MEMORY_SCOPE_AGENT);
    while (__hip_atomic_load(bar, __ATOMIC_RELAXED, __HIP_MEMORY_SCOPE_AGENT) < target) {
      __builtin_amdgcn_s_sleep(1);
    }
  }
  __syncthreads();
}

// 16-col x 32-k FMA section, float2-packed so the compiler can emit
// v_pk_fma_f32 (fp32 peak is the packed rate). acc[c] holds (even-k, odd-k)
// partials for column c. W addresses are wave-uniform (kq via readfirstlane)
// -> scalar s_loads on the SMEM pipe, L2-resident.
__device__ __forceinline__ void fma16(f32x2 acc[16], const f32x4 h[8], const float* Wc) {
#pragma unroll 4
  for (int c = 0; c < 16; ++c) {
    const float* w = Wc + (size_t)c * HID;
    f32x2 s = acc[c];
#pragma unroll
    for (int r = 0; r < 8; ++r) {
      float4 wv = *(const float4*)(w + r * 4);
      f32x2 h01; h01.x = h[r].x; h01.y = h[r].y;
      f32x2 h23; h23.x = h[r].z; h23.y = h[r].w;
      f32x2 w01; w01.x = wv.x; w01.y = wv.y;
      f32x2 w23; w23.x = wv.z; w23.y = wv.w;
      s += h01 * w01;
      s += h23 * w23;
    }
    acc[c] = s;
  }
}

// Dot engine: 16 cols over a private K-slice of 128, explicit A/B register
// double-buffer with counted vmcnt. FIFO vmcnt semantics keep the counted
// waits safe with the (older) epilogue prefetch still in flight.
__device__ __forceinline__ void dot_engine(const float* hb, const float* Wb, f32x2 acc[16]) {
  f32x4 A[8], B[8];
#pragma unroll
  for (int r = 0; r < 8; ++r) A[r] = gload4(hb + r * 4);
#pragma unroll
  for (int r = 0; r < 8; ++r) B[r] = gload4(hb + 32 + r * 4);
  WAITV(8);                 // A ready (newest 8 = B still in flight)
  fma16(acc, A, Wb);
#pragma unroll
  for (int r = 0; r < 8; ++r) A[r] = gload4(hb + 64 + r * 4);
  WAITV(8);                 // B ready
  fma16(acc, B, Wb + 32);
#pragma unroll
  for (int r = 0; r < 8; ++r) B[r] = gload4(hb + 96 + r * 4);
  WAITV(8);                 // A(ch2) ready
  fma16(acc, A, Wb + 64);
  WAITV(0);                 // B(ch3) + epilogue prefetch ready
  fma16(acc, B, Wb + 96);
}

// ---------------------------------------------------------------------------
// Persistent cooperative pipelined recurrence, 256 blocks x 512 threads.
// Roles (blk>>6), iteration i:
//   3: ig0[t=i]   = x[t] @ Wx0^T + bx0 + bh0       -> io[t]      (sc1 store)
//   0: h0[t=i-1]  = tanh(ig0[t] + h0[t-1] @ Wh0^T) -> slot t&m   (sc1 store)
//   1: ig1[t=i-2] = h0[t] @ Wx1^T + bx1 + bh1      -> slot t&m   (sc1 store)
//   2: h1[t=i-3]  = tanh(ig1[t] + h1[t-1] @ Wh1^T); io[t] = 10*h1 (plain)
// ---------------------------------------------------------------------------
__global__ __launch_bounds__(512, 2) void rnn_step(
    const float* __restrict__ x,
    float* io,                          // d_out: ig0 scratch AND output sink
    const float* __restrict__ h0_init,  // [2][B][H]
    const float* __restrict__ Wx,       // [2][H][H]
    const float* __restrict__ Wh,       // [2][H][H]
    const float* __restrict__ bx,       // [2][H]
    const float* __restrict__ bh,       // [2][H]
    float* __restrict__ ws,
    unsigned P, unsigned mask)
{
  __shared__ __align__(16) float red[8 * 64 * RSTRIDE];   // 40 KB
  const int tid  = threadIdx.x;
  const int blk  = blockIdx.x;
  const int role = blk >> 6;                 // 0..3
  const int c0   = (blk & 63) << 4;          // 16 cols per block
  const int b    = tid & 63;
  const int kq   = __builtin_amdgcn_readfirstlane(tid >> 6); // wave id 0..7

  float* h0base = ws;
  float* h1base = ws + (size_t)P * NB;
  float* igbase = ws + (size_t)2 * P * NB;
  unsigned* bar = (unsigned*)(ws + (size_t)3 * P * NB);

  const float* W = (role == 3) ? Wx
                 : (role == 0) ? Wh
                 : (role == 1) ? (Wx + (size_t)HID * HID)
                 :               (Wh + (size_t)HID * HID);
  const float* Wb = W + (size_t)c0 * HID + kq * 128;

  // Epilogue output assignment: 2 outputs per thread, o = 2*tid, 2*tid+1.
  const int o0 = tid * 2;
  const int b1 = o0 >> 4;                    // batch row of outputs
  const int c1 = o0 & 15;                    // local col (even)
  const size_t rb = (size_t)b1 * HID + c0 + c1;

  float bsum0 = 0.f, bsum1 = 0.f;
  if (role == 1) {
    bsum0 = bx[HID + c0 + c1]     + bh[HID + c0 + c1];
    bsum1 = bx[HID + c0 + c1 + 1] + bh[HID + c0 + c1 + 1];
  } else if (role == 3) {
    bsum0 = bx[c0 + c1]     + bh[c0 + c1];
    bsum1 = bx[c0 + c1 + 1] + bh[c0 + c1 + 1];
  }

  for (int i = 0; i < NITER; ++i) {
    // Periodic coherence fence: invalidate L1+L2 once per slot-rotation
    // period (grid-uniform condition). Write-through stores guarantee no
    // data lives only in a cache, so this is always safe; it kills any
    // cached slab line before its slot is re-read (see proof above).
    if ((i & (int)mask) == 0 && i) {
      __builtin_amdgcn_fence(__ATOMIC_ACQUIRE, "agent");
    }

    bool active;
    int t;
    const float* src;
    if (role == 3)      { t = i;     active = (i <= 511);           src = x + (size_t)t * NB; }
    else if (role == 0) { t = i - 1; active = (i >= 1 && i <= 512);
                          src = (t == 0) ? h0_init : h0base + (size_t)((t - 1) & mask) * NB; }
    else if (role == 1) { t = i - 2; active = (i >= 2 && i <= 513);
                          src = h0base + (size_t)(t & mask) * NB; }
    else                { t = i - 3; active = (i >= 3 && i <= 514);
                          src = (t == 0) ? (h0_init + NB) : h1base + (size_t)((t - 1) & mask) * NB; }

    if (active) {
      // Prefetch epilogue operands early (produced last iteration; plain
      // cached loads — io[t] is write-once, ig1 slot covered by fence rule).
      f32x2 e = { 0.f, 0.f };
      if (role == 0)      e = gload2(io + (size_t)t * NB + rb);
      else if (role == 2) e = gload2(igbase + (size_t)(t & mask) * NB + rb);

      const float* hb = src + (size_t)b * HID + kq * 128;  // private K-slice

      f32x2 acc[16];
#pragma unroll
      for (int c = 0; c < 16; ++c) acc[c] = f32x2{0.f, 0.f};

      dot_engine(hb, Wb, acc);

      // Collapse even/odd-k partials, then kq-reduction through LDS.
      float accs[16];
#pragma unroll
      for (int c = 0; c < 16; ++c) accs[c] = acc[c].x + acc[c].y;

      float* rrow = &red[(kq * 64 + b) * RSTRIDE];
      *(float4*)(rrow + 0)  = make_float4(accs[0],  accs[1],  accs[2],  accs[3]);
      *(float4*)(rrow + 4)  = make_float4(accs[4],  accs[5],  accs[6],  accs[7]);
      *(float4*)(rrow + 8)  = make_float4(accs[8],  accs[9],  accs[10], accs[11]);
      *(float4*)(rrow + 12) = make_float4(accs[12], accs[13], accs[14], accs[15]);
      __syncthreads();

      float s0 = 0.f, s1 = 0.f;
#pragma unroll
      for (int q = 0; q < 8; ++q) {
        s0 += red[(q * 64 + b1) * RSTRIDE + c1];
        s1 += red[(q * 64 + b1) * RSTRIDE + c1 + 1];
      }

      if (role == 3) {
        f32x2 o = { s0 + bsum0, s1 + bsum1 };
        gstore2_coh(io + (size_t)t * NB + rb, o);
      } else if (role == 0) {
        f32x2 o = { tanhf(s0 + e.x), tanhf(s1 + e.y) };
        gstore2_coh(h0base + (size_t)(t & mask) * NB + rb, o);
      } else if (role == 1) {
        f32x2 o = { s0 + bsum0, s1 + bsum1 };
        gstore2_coh(igbase + (size_t)(t & mask) * NB + rb, o);
      } else {
        float t0 = tanhf(s0 + e.x);
        float t1 = tanhf(s1 + e.y);
        f32x2 o = { t0, t1 };
        gstore2_coh(h1base + (size_t)(t & mask) * NB + rb, o);
        // Final output: plain store; kernel-end release flushes dirty L2.
        *(float2*)&io[(size_t)t * NB + rb] = make_float2(10.f * t0, 10.f * t1);
      }
      // red reuse next iter is fenced by gbar's __syncthreads.
    }
    gbar(bar, (unsigned)(NBLK * (i + 1)));
  }
}

// ---------------------------------------------------------------------------
// Finalize: h_n = [h0[511], h1[511]] (slot 511&mask; written by sc1
// write-through stores -> fresh at the MALL; this dispatch's acquire
// invalidates caches so plain loads see it).
// ---------------------------------------------------------------------------
__global__ __launch_bounds__(256) void finalize_hn(
    const float* __restrict__ ws, float* __restrict__ out, unsigned P, unsigned mask)
{
  const int g = blockIdx.x * 256 + threadIdx.x;     // 0..131071
  const float* h0f = ws + (size_t)(511u & mask) * NB;
  const float* h1f = ws + (size_t)(P + (511u & mask)) * NB;
  const float v = (g < NB) ? h0f[g] : h1f[g - NB];
  out[(size_t)TSEQ * NB + g] = v;
}

// ---------------------------------------------------------------------------
extern "C" void kernel_launch(void* const* d_in, const int* in_sizes, int n_in,
                              void* d_out, int out_size, void* d_ws, size_t ws_size,
                              hipStream_t stream) {
  const float* x  = (const float*)d_in[0];
  const float* h0 = (const float*)d_in[1];
  const float* Wx = (const float*)d_in[2];
  const float* bx = (const float*)d_in[3];
  const float* Wh = (const float*)d_in[4];
  const float* bh = (const float*)d_in[5];
  float* out = (float*)d_out;
  float* ws  = (float*)d_ws;

  // Pick the deepest slot rotation that fits the workspace (16 -> 12.6 MB).
  // P=2 floor has byte-identical footprint to the previously-verified layout.
  unsigned P = 16;
  while (P > 2 && ((size_t)3 * P * NB + 16) * sizeof(float) > ws_size) P >>= 1;
  unsigned mask = P - 1;

  // Zero the barrier counter (stream-ordered, graph-capture safe).
  hipMemsetAsync(ws + (size_t)3 * P * NB, 0, sizeof(unsigned), stream);

  float* io = out;
  void* args[] = { &x, &io, &h0, &Wx, &Wh, &bx, &bh, &ws, &P, &mask };
  hipLaunchCooperativeKernel((const void*)rnn_step, dim3(NBLK), dim3(512),
                             args, 0, stream);

  finalize_hn<<<dim3(512), dim3(256), 0, stream>>>(ws, out, P, mask);
}